// Round 3
// baseline (2376.223 us; speedup 1.0000x reference)
//
#include <hip/hip_runtime.h>
#include <hip/hip_bf16.h>
#include <math.h>

typedef __bf16 bf16;
typedef __bf16 bf16x8 __attribute__((ext_vector_type(8)));
typedef float  f32x4  __attribute__((ext_vector_type(4)));

#define HID    2048
#define INTER_ 8192
#define SEQ    2048
#define NTOK   8192
#define HD     128

__device__ __forceinline__ f32x4 mfma16(bf16x8 a, bf16x8 b, f32x4 c){
  return __builtin_amdgcn_mfma_f32_16x16x32_bf16(a, b, c, 0, 0, 0);
}

__device__ __forceinline__ void gl_lds16(const void* g, void* l){
  __builtin_amdgcn_global_load_lds((const __attribute__((address_space(1))) void*)g,
                                   (__attribute__((address_space(3))) void*)l,
                                   16, 0, 0);
}

// ---- fp32 [K][N]  ->  bf16 [N][K] (transpose + convert) ----
__global__ __launch_bounds__(256)
void convT_k(const float* __restrict__ in, bf16* __restrict__ out, int K, int N)
{
  __shared__ float tile[32][33];
  const int k0 = blockIdx.x * 32, n0 = blockIdx.y * 32;
  const int tx = threadIdx.x & 31, ty = threadIdx.x >> 5;  // 32 x 8
#pragma unroll
  for (int r = 0; r < 4; r++)
    tile[ty + r*8][tx] = in[(size_t)(k0 + ty + r*8) * N + n0 + tx];
  __syncthreads();
#pragma unroll
  for (int r = 0; r < 4; r++)
    out[(size_t)(n0 + ty + r*8) * K + k0 + tx] = (bf16)tile[tx][ty + r*8];
}

// ---- LayerNorm (fp32 in, bf16 out), one block per token ----
__global__ __launch_bounds__(256)
void ln_k(const float* __restrict__ x, const float* __restrict__ gamma,
          const float* __restrict__ beta, bf16* __restrict__ out)
{
  const int row = blockIdx.x, t = threadIdx.x;
  const float* xr = x + (size_t)row * HID;
  const float4 a = ((const float4*)xr)[t*2];
  const float4 b = ((const float4*)xr)[t*2 + 1];
  float s  = a.x+a.y+a.z+a.w + b.x+b.y+b.z+b.w;
  float ss = a.x*a.x+a.y*a.y+a.z*a.z+a.w*a.w + b.x*b.x+b.y*b.y+b.z*b.z+b.w*b.w;
#pragma unroll
  for (int m = 32; m; m >>= 1){ s += __shfl_xor(s, m); ss += __shfl_xor(ss, m); }
  __shared__ float red[8];
  const int w = t >> 6;
  if ((t & 63) == 0){ red[w*2] = s; red[w*2+1] = ss; }
  __syncthreads();
  s  = red[0] + red[2] + red[4] + red[6];
  ss = red[1] + red[3] + red[5] + red[7];
  const float mean = s * (1.0f/HID);
  const float var  = ss * (1.0f/HID) - mean*mean;
  const float rs   = rsqrtf(var + 1e-5f);
  const int c = t * 8;
  const float xe[8] = {a.x,a.y,a.z,a.w,b.x,b.y,b.z,b.w};
  bf16x8 o;
#pragma unroll
  for (int e = 0; e < 8; e++)
    o[e] = (bf16)((xe[e] - mean) * rs * gamma[c+e] + beta[c+e]);
  *(bf16x8*)(out + (size_t)row*HID + c) = o;
}

// ---- GEMM: C[M][N] = A[M][K] * BT[N][K]^T, 128x128 tile, BK=32, 4 waves ----
// EPI 0: QKV split (bias,bias2 -> o0=q bf16, o1=k, o2=v)
// EPI 1: + bias + res -> outf fp32
// EPI 2: + bias, gelu -> o0 bf16 (stride INTER_)
// EPI 3: + bias + outf(read) -> outf fp32
template<int EPI>
__global__ __launch_bounds__(256)
void gemm_bt(const bf16* __restrict__ A, const bf16* __restrict__ BT,
             int M, int N, int K,
             const float* __restrict__ bias, const float* __restrict__ bias2,
             const float* __restrict__ res, float* __restrict__ outf,
             bf16* __restrict__ o0, bf16* __restrict__ o1, bf16* __restrict__ o2)
{
  __shared__ bf16 lA[128*32];
  __shared__ bf16 lB[128*32];
  const int t = threadIdx.x, l = t & 63, w = t >> 6;
  const int m0 = blockIdx.x * 128, n0 = blockIdx.y * 128;
  const int wm = (w >> 1) * 64, wn = (w & 1) * 64;
  const int g16 = l >> 4, c16 = l & 15;
  const f32x4 z4 = {0.f, 0.f, 0.f, 0.f};
  f32x4 acc[4][4];
#pragma unroll
  for (int i = 0; i < 4; i++)
#pragma unroll
    for (int j = 0; j < 4; j++) acc[i][j] = z4;

  const int srow = (t * 16) >> 6;          // staging row 0..63
  const int scol = ((t * 16) & 63) >> 1;   // bf16 elem offset within 32-wide row

  for (int k0 = 0; k0 < K; k0 += 32){
    __syncthreads();
    gl_lds16(A  + (size_t)(m0 + srow)      * K + k0 + scol, (char*)lA + t*16);
    gl_lds16(A  + (size_t)(m0 + 64 + srow) * K + k0 + scol, (char*)lA + 4096 + t*16);
    gl_lds16(BT + (size_t)(n0 + srow)      * K + k0 + scol, (char*)lB + t*16);
    gl_lds16(BT + (size_t)(n0 + 64 + srow) * K + k0 + scol, (char*)lB + 4096 + t*16);
    __syncthreads();
    bf16x8 af[4], bfv[4];
#pragma unroll
    for (int i = 0; i < 4; i++){
      af[i]  = *(const bf16x8*)&lA[(wm + i*16 + c16)*32 + g16*8];
      bfv[i] = *(const bf16x8*)&lB[(wn + i*16 + c16)*32 + g16*8];
    }
#pragma unroll
    for (int i = 0; i < 4; i++)
#pragma unroll
      for (int j = 0; j < 4; j++)
        acc[i][j] = mfma16(af[i], bfv[j], acc[i][j]);
  }

#pragma unroll
  for (int i = 0; i < 4; i++)
#pragma unroll
    for (int j = 0; j < 4; j++)
#pragma unroll
      for (int r = 0; r < 4; r++){
        const int row = m0 + wm + i*16 + g16*4 + r;
        const int col = n0 + wn + j*16 + c16;
        const float v = acc[i][j][r];
        if constexpr (EPI == 0){
          if (col < HID){
            o0[(size_t)row*HID + col] = (bf16)(v + bias[col]);
          } else {
            const int nn = col - HID;
            const float vv = v + bias2[nn];
            if (nn < HD) o1[(size_t)row*HD + nn]      = (bf16)vv;
            else         o2[(size_t)row*HD + nn - HD] = (bf16)vv;
          }
        } else if constexpr (EPI == 1){
          outf[(size_t)row*HID + col] = v + bias[col] + res[(size_t)row*HID + col];
        } else if constexpr (EPI == 2){
          const float u = v + bias[col];
          const float gg = 0.5f * u * (1.0f + tanhf(0.7978845608028654f * (u + 0.044715f*u*u*u)));
          o0[(size_t)row*INTER_ + col] = (bf16)gg;
        } else {
          float* op = outf + (size_t)row*HID + col;
          *op = v + bias[col] + *op;
        }
      }
}

// ---- causal MQA flash attention: 1 block per (b, h, 64 q-rows), 4 waves x 16 rows ----
// NOTE: ob may alias qb (each block reads its own Q region into registers
// before any block writes it; Q regions are block-private).
__global__ __launch_bounds__(256)
void attn_k(const bf16* __restrict__ qb, const bf16* __restrict__ kb,
            const bf16* __restrict__ vb, bf16* ob)
{
  __shared__ bf16 pl[4][16][32];   // per-wave P tile (q-local x key-local)
  __shared__ bf16 vt[128][32];     // V^T tile: [d][t]
  const int bid = blockIdx.x;
  const int b  = bid >> 9;
  const int h  = (bid >> 5) & 15;
  const int q0 = (bid & 31) * 64;
  const int t = threadIdx.x, w = t >> 6, l = t & 63;
  const int g16 = l >> 4, c16 = l & 15;
  const float scale = 0.08838834764831845f;   // 128^-0.5
  const f32x4 z4 = {0.f,0.f,0.f,0.f};

  const bf16* qrow = qb + (size_t)(b*SEQ + q0 + w*16 + c16)*HID + h*HD + g16*8;
  bf16x8 qf[4];
#pragma unroll
  for (int d = 0; d < 4; d++) qf[d] = *(const bf16x8*)(qrow + d*32);

  const bf16* kbase = kb + (size_t)b*SEQ*HD;
  const bf16* vbase = vb + (size_t)b*SEQ*HD;

  f32x4 acc[8];
#pragma unroll
  for (int i = 0; i < 8; i++) acc[i] = z4;
  float mrun[4] = {-1e30f,-1e30f,-1e30f,-1e30f};
  float lrun[4] = {0.f,0.f,0.f,0.f};
  const int qgb = q0 + w*16 + g16*4;          // + r = global q row
  const int ntile = (q0 >> 5) + 2;            // uniform across waves (masked)
  const int vrow = t >> 3, vdb = (t & 7) * 16;

  for (int kt = 0; kt < ntile; kt++){
    const int t0 = kt * 32;
    // ---- QK^T: A=Q (m=q), B=K^T (n=key), contraction over d in 4 chunks ----
    f32x4 s0v = z4, s1v = z4;
    const bf16* kr0 = kbase + (size_t)(t0 + c16)*HD + g16*8;
    const bf16* kr1 = kbase + (size_t)(t0 + 16 + c16)*HD + g16*8;
#pragma unroll
    for (int d = 0; d < 4; d++){
      s0v = mfma16(qf[d], *(const bf16x8*)(kr0 + d*32), s0v);
      s1v = mfma16(qf[d], *(const bf16x8*)(kr1 + d*32), s1v);
    }
    // early V loads (hide under softmax; consumed after barrier)
    const bf16* vr = vbase + (size_t)(t0 + vrow)*HD + vdb;
    const bf16x8 va0 = *(const bf16x8*)vr;
    const bf16x8 va1 = *(const bf16x8*)(vr + 8);

    // ---- online softmax (row = 16 lanes of a group) ----
    float coef[4], p0a[4], p1a[4];
#pragma unroll
    for (int r = 0; r < 4; r++){
      float s0 = s0v[r]*scale, s1 = s1v[r]*scale;
      const int qg = qgb + r;
      if (t0 + c16 > qg)      s0 = -1e30f;
      if (t0 + 16 + c16 > qg) s1 = -1e30f;
      float mv = fmaxf(s0, s1);
#pragma unroll
      for (int mk = 1; mk < 16; mk <<= 1) mv = fmaxf(mv, __shfl_xor(mv, mk));
      const float mn = fmaxf(mrun[r], mv);
      const float p0 = __expf(s0 - mn), p1 = __expf(s1 - mn);
      float ps = p0 + p1;
#pragma unroll
      for (int mk = 1; mk < 16; mk <<= 1) ps += __shfl_xor(ps, mk);
      coef[r] = __expf(mrun[r] - mn);
      lrun[r] = lrun[r]*coef[r] + ps;
      mrun[r] = mn;
      p0a[r] = p0; p1a[r] = p1;
    }
#pragma unroll
    for (int dt = 0; dt < 8; dt++){
#pragma unroll
      for (int r = 0; r < 4; r++) acc[dt][r] *= coef[r];
    }
    __syncthreads();                     // prior-iter LDS reads done
#pragma unroll
    for (int r = 0; r < 4; r++){
      pl[w][g16*4 + r][c16]      = (bf16)p0a[r];
      pl[w][g16*4 + r][16 + c16] = (bf16)p1a[r];
    }
#pragma unroll
    for (int e = 0; e < 8; e++){
      vt[vdb + e][vrow]     = va0[e];
      vt[vdb + 8 + e][vrow] = va1[e];
    }
    __syncthreads();                     // LDS writes visible
    // ---- PV: A=P (m=q, k=key), B=V (k=key, n=d) from V^T LDS ----
    const bf16x8 pa = *(const bf16x8*)&pl[w][c16][g16*8];
#pragma unroll
    for (int dt = 0; dt < 8; dt++){
      const bf16x8 vf = *(const bf16x8*)&vt[dt*16 + c16][g16*8];
      acc[dt] = mfma16(pa, vf, acc[dt]);
    }
  }
#pragma unroll
  for (int r = 0; r < 4; r++){
    const float inv = 1.0f / lrun[r];
    bf16* orow = ob + (size_t)(b*SEQ + qgb + r)*HID + h*HD;
#pragma unroll
    for (int dt = 0; dt < 8; dt++)
      orow[dt*16 + c16] = (bf16)(acc[dt][r] * inv);
  }
}

extern "C" void kernel_launch(void* const* d_in, const int* in_sizes, int n_in,
                              void* d_out, int out_size, void* d_ws, size_t ws_size,
                              hipStream_t stream)
{
  const float* x    = (const float*)d_in[0];
  const float* ln1g = (const float*)d_in[1];
  const float* ln1b = (const float*)d_in[2];
  const float* ln2g = (const float*)d_in[3];
  const float* ln2b = (const float*)d_in[4];
  const float* wq   = (const float*)d_in[5];
  const float* bq   = (const float*)d_in[6];
  const float* wkv  = (const float*)d_in[7];
  const float* bkv  = (const float*)d_in[8];
  const float* wo   = (const float*)d_in[9];
  const float* bo   = (const float*)d_in[10];
  const float* wfc  = (const float*)d_in[11];
  const float* bfc  = (const float*)d_in[12];
  const float* wpr  = (const float*)d_in[13];
  const float* bpr  = (const float*)d_in[14];
  float* out = (float*)d_out;
  (void)in_sizes; (void)n_in; (void)out_size; (void)ws_size;

  // ---- workspace carve: ~190 MB total (was ~324 MB -> suspected ws overrun) ----
  char* p = (char*)d_ws;
  auto carve = [&](size_t n){ char* r = p; p += (n + 255) & ~(size_t)255; return r; };
  bf16* wqkvT = (bf16*)carve((size_t)2304*2048*2);   //  9.4 MB
  bf16* woT   = (bf16*)carve((size_t)2048*2048*2);   //  8.4 MB
  bf16* wfcT  = (bf16*)carve((size_t)8192*2048*2);   // 33.6 MB
  bf16* wprT  = (bf16*)carve((size_t)2048*8192*2);   // 33.6 MB
  bf16* hbuf  = (bf16*)carve((size_t)NTOK*2048*2);   // 33.6 MB (LN1 out, later LN2 out)
  bf16* qbuf  = (bf16*)carve((size_t)NTOK*2048*2);   // 33.6 MB (Q; attn writes output here too)
  bf16* kbuf  = (bf16*)carve((size_t)NTOK*128*2);    //  2.1 MB
  bf16* vbuf  = (bf16*)carve((size_t)NTOK*128*2);    //  2.1 MB
  bf16* gbuf  = (bf16*)carve((size_t)2048*8192*2);   // 33.6 MB (MLP inter, 2048-token chunk)

  dim3 B(256);
  // weight convert + transpose (runs every call; ws is re-poisoned each launch)
  convT_k<<<dim3(64, 64),  B, 0, stream>>>(wq,  wqkvT, 2048, 2048);
  convT_k<<<dim3(64, 8),   B, 0, stream>>>(wkv, wqkvT + (size_t)2048*2048, 2048, 256);
  convT_k<<<dim3(64, 64),  B, 0, stream>>>(wo,  woT,  2048, 2048);
  convT_k<<<dim3(64, 256), B, 0, stream>>>(wfc, wfcT, 2048, 8192);
  convT_k<<<dim3(256, 64), B, 0, stream>>>(wpr, wprT, 8192, 2048);

  ln_k<<<NTOK, B, 0, stream>>>(x, ln1g, ln1b, hbuf);
  gemm_bt<0><<<dim3(64, 18), B, 0, stream>>>(hbuf, wqkvT, NTOK, 2304, 2048,
                                             bq, bkv, nullptr, nullptr, qbuf, kbuf, vbuf);
  attn_k<<<2048, B, 0, stream>>>(qbuf, kbuf, vbuf, qbuf /*in-place*/);
  gemm_bt<1><<<dim3(64, 16), B, 0, stream>>>(qbuf, woT, NTOK, 2048, 2048,
                                             bo, nullptr, x, out, nullptr, nullptr, nullptr);
  ln_k<<<NTOK, B, 0, stream>>>(out, ln2g, ln2b, hbuf);
  // MLP in 4 token-chunks of 2048 rows to bound gbuf at 33.6 MB
  for (int c = 0; c < 4; c++){
    const size_t ro = (size_t)c * 2048;
    gemm_bt<2><<<dim3(16, 64), B, 0, stream>>>(hbuf + ro*HID, wfcT, 2048, 8192, 2048,
                                               bfc, nullptr, nullptr, nullptr, gbuf, nullptr, nullptr);
    gemm_bt<3><<<dim3(16, 16), B, 0, stream>>>(gbuf, wprT, 2048, 2048, 8192,
                                               bpr, nullptr, nullptr, out + ro*HID, nullptr, nullptr, nullptr);
  }
}

// Round 8
// 1992.414 us; speedup vs baseline: 1.1926x; 1.1926x over previous
//
#include <hip/hip_runtime.h>
#include <hip/hip_bf16.h>
#include <math.h>

typedef __bf16 bf16;
typedef __bf16 bf16x8 __attribute__((ext_vector_type(8)));
typedef float  f32x4  __attribute__((ext_vector_type(4)));

#define HID    2048
#define INTER_ 8192
#define SEQ    2048
#define NTOK   8192
#define HD     128

__device__ __forceinline__ f32x4 mfma16(bf16x8 a, bf16x8 b, f32x4 c){
  return __builtin_amdgcn_mfma_f32_16x16x32_bf16(a, b, c, 0, 0, 0);
}

__device__ __forceinline__ void gl_lds16(const void* g, void* l){
  __builtin_amdgcn_global_load_lds((const __attribute__((address_space(1))) void*)g,
                                   (__attribute__((address_space(3))) void*)l,
                                   16, 0, 0);
}

// ---- fp32 [K][N]  ->  bf16 [N][K] (transpose + convert) ----
__global__ __launch_bounds__(256)
void convT_k(const float* __restrict__ in, bf16* __restrict__ out, int K, int N)
{
  __shared__ float tile[32][33];
  const int k0 = blockIdx.x * 32, n0 = blockIdx.y * 32;
  const int tx = threadIdx.x & 31, ty = threadIdx.x >> 5;  // 32 x 8
#pragma unroll
  for (int r = 0; r < 4; r++)
    tile[ty + r*8][tx] = in[(size_t)(k0 + ty + r*8) * N + n0 + tx];
  __syncthreads();
#pragma unroll
  for (int r = 0; r < 4; r++)
    out[(size_t)(n0 + ty + r*8) * K + k0 + tx] = (bf16)tile[tx][ty + r*8];
}

// ---- LayerNorm (fp32 in, bf16 out), one block per token ----
__global__ __launch_bounds__(256)
void ln_k(const float* __restrict__ x, const float* __restrict__ gamma,
          const float* __restrict__ beta, bf16* __restrict__ out)
{
  const int row = blockIdx.x, t = threadIdx.x;
  const float* xr = x + (size_t)row * HID;
  const float4 a = ((const float4*)xr)[t*2];
  const float4 b = ((const float4*)xr)[t*2 + 1];
  float s  = a.x+a.y+a.z+a.w + b.x+b.y+b.z+b.w;
  float ss = a.x*a.x+a.y*a.y+a.z*a.z+a.w*a.w + b.x*b.x+b.y*b.y+b.z*b.z+b.w*b.w;
#pragma unroll
  for (int m = 32; m; m >>= 1){ s += __shfl_xor(s, m); ss += __shfl_xor(ss, m); }
  __shared__ float red[8];
  const int w = t >> 6;
  if ((t & 63) == 0){ red[w*2] = s; red[w*2+1] = ss; }
  __syncthreads();
  s  = red[0] + red[2] + red[4] + red[6];
  ss = red[1] + red[3] + red[5] + red[7];
  const float mean = s * (1.0f/HID);
  const float var  = ss * (1.0f/HID) - mean*mean;
  const float rs   = rsqrtf(var + 1e-5f);
  const int c = t * 8;
  const float xe[8] = {a.x,a.y,a.z,a.w,b.x,b.y,b.z,b.w};
  bf16x8 o;
#pragma unroll
  for (int e = 0; e < 8; e++)
    o[e] = (bf16)((xe[e] - mean) * rs * gamma[c+e] + beta[c+e]);
  *(bf16x8*)(out + (size_t)row*HID + c) = o;
}

// ---- GEMM: C[M][N] = A[M][K] * BT[N][K]^T, 128x128 tile, BK=32, 4 waves ----
// EPI 0: QKV split -> o0=q bf16 [tok][2048], o1=k [tok][128], o2=V^T [b][d][s]
// EPI 1: + bias + res -> outf fp32
// EPI 2: + bias, gelu -> o0 bf16 (stride INTER_)
// EPI 3: + bias + outf(read) -> outf fp32
template<int EPI>
__global__ __launch_bounds__(256)
void gemm_bt(const bf16* __restrict__ A, const bf16* __restrict__ BT,
             int M, int N, int K,
             const float* __restrict__ bias, const float* __restrict__ bias2,
             const float* __restrict__ res, float* __restrict__ outf,
             bf16* __restrict__ o0, bf16* __restrict__ o1, bf16* __restrict__ o2)
{
  __shared__ bf16 lA[128*32];
  __shared__ bf16 lB[128*32];
  const int t = threadIdx.x, l = t & 63, w = t >> 6;
  // XCD-aware bijective block swizzle (all launches have nwg % 8 == 0)
  int bx = blockIdx.x, by = blockIdx.y;
  {
    const int nwg = gridDim.x * gridDim.y;
    if ((nwg & 7) == 0){
      int wg = by * gridDim.x + bx;
      const int per = nwg >> 3;
      wg = (wg & 7) * per + (wg >> 3);
      bx = wg % gridDim.x; by = wg / gridDim.x;
    }
  }
  const int m0 = bx * 128, n0 = by * 128;
  const int wm = (w >> 1) * 64, wn = (w & 1) * 64;
  const int g16 = l >> 4, c16 = l & 15;
  const f32x4 z4 = {0.f, 0.f, 0.f, 0.f};
  f32x4 acc[4][4];
#pragma unroll
  for (int i = 0; i < 4; i++)
#pragma unroll
    for (int j = 0; j < 4; j++) acc[i][j] = z4;

  const int srow = (t * 16) >> 6;          // staging row 0..63
  const int scol = ((t * 16) & 63) >> 1;   // bf16 elem offset within 32-wide row

  for (int k0 = 0; k0 < K; k0 += 32){
    __syncthreads();
    gl_lds16(A  + (size_t)(m0 + srow)      * K + k0 + scol, (char*)lA + t*16);
    gl_lds16(A  + (size_t)(m0 + 64 + srow) * K + k0 + scol, (char*)lA + 4096 + t*16);
    gl_lds16(BT + (size_t)(n0 + srow)      * K + k0 + scol, (char*)lB + t*16);
    gl_lds16(BT + (size_t)(n0 + 64 + srow) * K + k0 + scol, (char*)lB + 4096 + t*16);
    __syncthreads();
    bf16x8 af[4], bfv[4];
#pragma unroll
    for (int i = 0; i < 4; i++){
      af[i]  = *(const bf16x8*)&lA[(wm + i*16 + c16)*32 + g16*8];
      bfv[i] = *(const bf16x8*)&lB[(wn + i*16 + c16)*32 + g16*8];
    }
#pragma unroll
    for (int i = 0; i < 4; i++)
#pragma unroll
      for (int j = 0; j < 4; j++)
        acc[i][j] = mfma16(af[i], bfv[j], acc[i][j]);
  }

#pragma unroll
  for (int i = 0; i < 4; i++)
#pragma unroll
    for (int j = 0; j < 4; j++)
#pragma unroll
      for (int r = 0; r < 4; r++){
        const int row = m0 + wm + i*16 + g16*4 + r;
        const int col = n0 + wn + j*16 + c16;
        const float v = acc[i][j][r];
        if constexpr (EPI == 0){
          if (col < HID){
            o0[(size_t)row*HID + col] = (bf16)(v + bias[col]);
          } else {
            const int nn = col - HID;
            const float vv = v + bias2[nn];
            if (nn < HD) o1[(size_t)row*HD + nn] = (bf16)vv;
            else {
              const int d = nn - HD;                 // V^T: [b][d][s]
              o2[((size_t)(row >> 11)*HD + d)*SEQ + (row & (SEQ-1))] = (bf16)vv;
            }
          }
        } else if constexpr (EPI == 1){
          outf[(size_t)row*HID + col] = v + bias[col] + res[(size_t)row*HID + col];
        } else if constexpr (EPI == 2){
          const float u = v + bias[col];
          const float gg = 0.5f * u * (1.0f + tanhf(0.7978845608028654f * (u + 0.044715f*u*u*u)));
          o0[(size_t)row*INTER_ + col] = (bf16)gg;
        } else {
          float* op = outf + (size_t)row*HID + col;
          *op = v + bias[col] + *op;
        }
      }
}

// ---- causal MQA flash attention v2: barrier-free, KVBLK=64, paired q-tiles ----
// grid 1024 = 4 b * 16 h * 16 pairs; block = 4 waves * 16 q-rows; passes (qb, 31-qb).
// K read row-major from global (L2); V read from global V^T [b][d][s]; P routed
// through per-wave LDS (no __syncthreads anywhere). ob may alias qb_ (block-private rows).
__global__ __launch_bounds__(256)
void attn_k(const bf16* __restrict__ qbuf, const bf16* __restrict__ kb,
            const bf16* __restrict__ vT, bf16* ob)
{
  __shared__ bf16 pl[4][16][64];
  const int bid0 = blockIdx.x;
  const int bid = ((bid0 & 7) << 7) + (bid0 >> 3);   // XCD swizzle (1024 blocks)
  const int b  = bid >> 8;
  const int h  = (bid >> 4) & 15;
  const int pr = bid & 15;
  const int t = threadIdx.x, w = t >> 6, l = t & 63;
  const int g16 = l >> 4, c16 = l & 15;
  const float scale = 0.08838834764831845f;   // 128^-0.5
  const f32x4 z4 = {0.f,0.f,0.f,0.f};
  const bf16* kbase = kb + (size_t)b*SEQ*HD;
  const bf16* vbase = vT + (size_t)b*HD*SEQ;

#pragma unroll
  for (int pass = 0; pass < 2; pass++){
    const int qb_i = pass ? (31 - pr) : pr;
    const int q0 = qb_i * 64;
    const bf16* qrow = qbuf + (size_t)(b*SEQ + q0 + w*16 + c16)*HID + h*HD + g16*8;
    bf16x8 qf[4];
#pragma unroll
    for (int dc = 0; dc < 4; dc++) qf[dc] = *(const bf16x8*)(qrow + dc*32);

    f32x4 acc[8];
#pragma unroll
    for (int i = 0; i < 8; i++) acc[i] = z4;
    float mrun[4] = {-1e30f,-1e30f,-1e30f,-1e30f};
    float lrun[4] = {0.f,0.f,0.f,0.f};
    const int qg_ = q0 + w*16 + g16*4;      // +r = global q row

    for (int kt = 0; kt <= qb_i; kt++){
      const int t0 = kt * 64;
      // ---- QK^T over 64 keys: 4 key-subtiles x 4 d-chunks ----
      f32x4 s[4] = {z4, z4, z4, z4};
#pragma unroll
      for (int ks = 0; ks < 4; ks++){
        const bf16* kr = kbase + (size_t)(t0 + ks*16 + c16)*HD + g16*8;
#pragma unroll
        for (int dc = 0; dc < 4; dc++)
          s[ks] = mfma16(qf[dc], *(const bf16x8*)(kr + dc*32), s[ks]);
      }
      const bool last = (kt == qb_i);
      // ---- online softmax: lane holds rows qg_+r, keys t0+ks*16+c16 ----
      float coef[4];
#pragma unroll
      for (int r = 0; r < 4; r++){
        float sv[4];
#pragma unroll
        for (int ks = 0; ks < 4; ks++) sv[ks] = s[ks][r] * scale;
        if (last){
          const int qg = qg_ + r;
#pragma unroll
          for (int ks = 0; ks < 4; ks++)
            if (t0 + ks*16 + c16 > qg) sv[ks] = -1e30f;
        }
        float mv = fmaxf(fmaxf(sv[0], sv[1]), fmaxf(sv[2], sv[3]));
#pragma unroll
        for (int mk = 1; mk < 16; mk <<= 1) mv = fmaxf(mv, __shfl_xor(mv, mk));
        const float mn = fmaxf(mrun[r], mv);
        float p[4], ps = 0.f;
#pragma unroll
        for (int ks = 0; ks < 4; ks++){ p[ks] = __expf(sv[ks] - mn); ps += p[ks]; }
#pragma unroll
        for (int mk = 1; mk < 16; mk <<= 1) ps += __shfl_xor(ps, mk);
        coef[r] = __expf(mrun[r] - mn);
        lrun[r] = lrun[r]*coef[r] + ps;
        mrun[r] = mn;
#pragma unroll
        for (int ks = 0; ks < 4; ks++)
          pl[w][g16*4 + r][ks*16 + c16] = (bf16)p[ks];
      }
#pragma unroll
      for (int dt = 0; dt < 8; dt++)
#pragma unroll
        for (int r = 0; r < 4; r++) acc[dt][r] *= coef[r];
      // ---- PV: A=P from per-wave LDS, B=V^T rows from global (L2) ----
      const bf16x8 pa0 = *(const bf16x8*)&pl[w][c16][g16*8];
      const bf16x8 pa1 = *(const bf16x8*)&pl[w][c16][32 + g16*8];
#pragma unroll
      for (int dt = 0; dt < 8; dt++){
        const bf16* vr = vbase + (size_t)(dt*16 + c16)*SEQ + t0 + g16*8;
        acc[dt] = mfma16(pa0, *(const bf16x8*)vr,        acc[dt]);
        acc[dt] = mfma16(pa1, *(const bf16x8*)(vr + 32), acc[dt]);
      }
    }
#pragma unroll
    for (int r = 0; r < 4; r++){
      const float inv = 1.0f / lrun[r];
      bf16* orow = ob + (size_t)(b*SEQ + qg_ + r)*HID + h*HD;
#pragma unroll
      for (int dt = 0; dt < 8; dt++)
        orow[dt*16 + c16] = (bf16)(acc[dt][r] * inv);
    }
  }
}

extern "C" void kernel_launch(void* const* d_in, const int* in_sizes, int n_in,
                              void* d_out, int out_size, void* d_ws, size_t ws_size,
                              hipStream_t stream)
{
  const float* x    = (const float*)d_in[0];
  const float* ln1g = (const float*)d_in[1];
  const float* ln1b = (const float*)d_in[2];
  const float* ln2g = (const float*)d_in[3];
  const float* ln2b = (const float*)d_in[4];
  const float* wq   = (const float*)d_in[5];
  const float* bq   = (const float*)d_in[6];
  const float* wkv  = (const float*)d_in[7];
  const float* bkv  = (const float*)d_in[8];
  const float* wo   = (const float*)d_in[9];
  const float* bo   = (const float*)d_in[10];
  const float* wfc  = (const float*)d_in[11];
  const float* bfc  = (const float*)d_in[12];
  const float* wpr  = (const float*)d_in[13];
  const float* bpr  = (const float*)d_in[14];
  float* out = (float*)d_out;
  (void)in_sizes; (void)n_in; (void)out_size;

  char* p = (char*)d_ws;
  auto carve = [&](size_t n){ char* r = p; p += (n + 255) & ~(size_t)255; return r; };
  bf16* wqkvT = (bf16*)carve((size_t)2304*2048*2);   //  9.4 MB
  bf16* woT   = (bf16*)carve((size_t)2048*2048*2);   //  8.4 MB
  bf16* wfcT  = (bf16*)carve((size_t)8192*2048*2);   // 33.6 MB
  bf16* wprT  = (bf16*)carve((size_t)2048*8192*2);   // 33.6 MB
  bf16* hbuf  = (bf16*)carve((size_t)NTOK*2048*2);   // 33.6 MB (LN1 out, later LN2 out)
  bf16* qbuf  = (bf16*)carve((size_t)NTOK*2048*2);   // 33.6 MB (Q; attn output in-place)
  bf16* kbuf  = (bf16*)carve((size_t)NTOK*128*2);    //  2.1 MB
  bf16* vbufT = (bf16*)carve((size_t)NTOK*128*2);    //  2.1 MB (V^T [b][d][s])
  const size_t fixed_bytes = 156237824;              // sum of the above (256-aligned)
  // MLP chunk rows: pick largest gbuf that fits ws (round-3 proved >=190MB works)
  size_t grows = 2048;
  if (ws_size >= fixed_bytes + (size_t)8192*8192*2)      grows = 8192;
  else if (ws_size >= fixed_bytes + (size_t)4096*8192*2) grows = 4096;
  bf16* gbuf  = (bf16*)carve((size_t)grows*8192*2);

  dim3 B(256);
  convT_k<<<dim3(64, 64),  B, 0, stream>>>(wq,  wqkvT, 2048, 2048);
  convT_k<<<dim3(64, 8),   B, 0, stream>>>(wkv, wqkvT + (size_t)2048*2048, 2048, 256);
  convT_k<<<dim3(64, 64),  B, 0, stream>>>(wo,  woT,  2048, 2048);
  convT_k<<<dim3(64, 256), B, 0, stream>>>(wfc, wfcT, 2048, 8192);
  convT_k<<<dim3(256, 64), B, 0, stream>>>(wpr, wprT, 8192, 2048);

  ln_k<<<NTOK, B, 0, stream>>>(x, ln1g, ln1b, hbuf);
  gemm_bt<0><<<dim3(64, 18), B, 0, stream>>>(hbuf, wqkvT, NTOK, 2304, 2048,
                                             bq, bkv, nullptr, nullptr, qbuf, kbuf, vbufT);
  attn_k<<<1024, B, 0, stream>>>(qbuf, kbuf, vbufT, qbuf /*in-place*/);
  gemm_bt<1><<<dim3(64, 16), B, 0, stream>>>(qbuf, woT, NTOK, 2048, 2048,
                                             bo, nullptr, x, out, nullptr, nullptr, nullptr);
  ln_k<<<NTOK, B, 0, stream>>>(out, ln2g, ln2b, hbuf);
  for (size_t c = 0; c < NTOK/grows; c++){
    const size_t ro = c * grows;
    gemm_bt<2><<<dim3(grows/128, 64), B, 0, stream>>>(hbuf + ro*HID, wfcT, (int)grows, 8192, 2048,
                                               bfc, nullptr, nullptr, nullptr, gbuf, nullptr, nullptr);
    gemm_bt<3><<<dim3(grows/128, 16), B, 0, stream>>>(gbuf, wprT, (int)grows, 2048, 8192,
                                               bpr, nullptr, nullptr, out + ro*HID, nullptr, nullptr, nullptr);
  }
}

// Round 9
// 1947.635 us; speedup vs baseline: 1.2201x; 1.0230x over previous
//
#include <hip/hip_runtime.h>
#include <hip/hip_bf16.h>
#include <math.h>

typedef __bf16 bf16;
typedef __bf16 bf16x8 __attribute__((ext_vector_type(8)));
typedef float  f32x4  __attribute__((ext_vector_type(4)));

#define HID    2048
#define INTER_ 8192
#define SEQ    2048
#define NTOK   8192
#define HD     128

__device__ __forceinline__ f32x4 mfma16(bf16x8 a, bf16x8 b, f32x4 c){
  return __builtin_amdgcn_mfma_f32_16x16x32_bf16(a, b, c, 0, 0, 0);
}

__device__ __forceinline__ void gl_lds16(const void* g, void* l){
  __builtin_amdgcn_global_load_lds((const __attribute__((address_space(1))) void*)g,
                                   (__attribute__((address_space(3))) void*)l,
                                   16, 0, 0);
}

// ---- fp32 [K][N]  ->  bf16 [N][K] (transpose + convert) ----
__global__ __launch_bounds__(256)
void convT_k(const float* __restrict__ in, bf16* __restrict__ out, int K, int N)
{
  __shared__ float tile[32][33];
  const int k0 = blockIdx.x * 32, n0 = blockIdx.y * 32;
  const int tx = threadIdx.x & 31, ty = threadIdx.x >> 5;  // 32 x 8
#pragma unroll
  for (int r = 0; r < 4; r++)
    tile[ty + r*8][tx] = in[(size_t)(k0 + ty + r*8) * N + n0 + tx];
  __syncthreads();
#pragma unroll
  for (int r = 0; r < 4; r++)
    out[(size_t)(n0 + ty + r*8) * K + k0 + tx] = (bf16)tile[tx][ty + r*8];
}

// ---- LayerNorm (fp32 in, bf16 out), one block per token ----
__global__ __launch_bounds__(256)
void ln_k(const float* __restrict__ x, const float* __restrict__ gamma,
          const float* __restrict__ beta, bf16* __restrict__ out)
{
  const int row = blockIdx.x, t = threadIdx.x;
  const float* xr = x + (size_t)row * HID;
  const float4 a = ((const float4*)xr)[t*2];
  const float4 b = ((const float4*)xr)[t*2 + 1];
  float s  = a.x+a.y+a.z+a.w + b.x+b.y+b.z+b.w;
  float ss = a.x*a.x+a.y*a.y+a.z*a.z+a.w*a.w + b.x*b.x+b.y*b.y+b.z*b.z+b.w*b.w;
#pragma unroll
  for (int m = 32; m; m >>= 1){ s += __shfl_xor(s, m); ss += __shfl_xor(ss, m); }
  __shared__ float red[8];
  const int w = t >> 6;
  if ((t & 63) == 0){ red[w*2] = s; red[w*2+1] = ss; }
  __syncthreads();
  s  = red[0] + red[2] + red[4] + red[6];
  ss = red[1] + red[3] + red[5] + red[7];
  const float mean = s * (1.0f/HID);
  const float var  = ss * (1.0f/HID) - mean*mean;
  const float rs   = rsqrtf(var + 1e-5f);
  const int c = t * 8;
  const float xe[8] = {a.x,a.y,a.z,a.w,b.x,b.y,b.z,b.w};
  bf16x8 o;
#pragma unroll
  for (int e = 0; e < 8; e++)
    o[e] = (bf16)((xe[e] - mean) * rs * gamma[c+e] + beta[c+e]);
  *(bf16x8*)(out + (size_t)row*HID + c) = o;
}

// ---- GEMM: C[M][N] = A[M][K] * BT[N][K]^T, 128x128 tile, BK=32, 4 waves ----
// EPI 0: QKV split -> o0=q bf16 [tok][2048], o1=k [tok][128], o2=V^T [b][d][s]
// EPI 1: + bias + res -> outf fp32
// EPI 2: + bias, gelu -> o0 bf16 (stride INTER_)
// EPI 3: + bias + outf(read) -> outf fp32
template<int EPI>
__global__ __launch_bounds__(256)
void gemm_bt(const bf16* __restrict__ A, const bf16* __restrict__ BT,
             int M, int N, int K,
             const float* __restrict__ bias, const float* __restrict__ bias2,
             const float* __restrict__ res, float* __restrict__ outf,
             bf16* __restrict__ o0, bf16* __restrict__ o1, bf16* __restrict__ o2)
{
  __shared__ bf16 lA[128*32];
  __shared__ bf16 lB[128*32];
  const int t = threadIdx.x, l = t & 63, w = t >> 6;
  // XCD-aware bijective block swizzle (all launches have nwg % 8 == 0)
  int bx = blockIdx.x, by = blockIdx.y;
  {
    const int nwg = gridDim.x * gridDim.y;
    if ((nwg & 7) == 0){
      int wg = by * gridDim.x + bx;
      const int per = nwg >> 3;
      wg = (wg & 7) * per + (wg >> 3);
      bx = wg % gridDim.x; by = wg / gridDim.x;
    }
  }
  const int m0 = bx * 128, n0 = by * 128;
  const int wm = (w >> 1) * 64, wn = (w & 1) * 64;
  const int g16 = l >> 4, c16 = l & 15;
  const f32x4 z4 = {0.f, 0.f, 0.f, 0.f};
  f32x4 acc[4][4];
#pragma unroll
  for (int i = 0; i < 4; i++)
#pragma unroll
    for (int j = 0; j < 4; j++) acc[i][j] = z4;

  const int srow = (t * 16) >> 6;          // staging row 0..63
  const int scol = ((t * 16) & 63) >> 1;   // bf16 elem offset within 32-wide row

  for (int k0 = 0; k0 < K; k0 += 32){
    __syncthreads();
    gl_lds16(A  + (size_t)(m0 + srow)      * K + k0 + scol, (char*)lA + t*16);
    gl_lds16(A  + (size_t)(m0 + 64 + srow) * K + k0 + scol, (char*)lA + 4096 + t*16);
    gl_lds16(BT + (size_t)(n0 + srow)      * K + k0 + scol, (char*)lB + t*16);
    gl_lds16(BT + (size_t)(n0 + 64 + srow) * K + k0 + scol, (char*)lB + 4096 + t*16);
    __syncthreads();
    bf16x8 af[4], bfv[4];
#pragma unroll
    for (int i = 0; i < 4; i++){
      af[i]  = *(const bf16x8*)&lA[(wm + i*16 + c16)*32 + g16*8];
      bfv[i] = *(const bf16x8*)&lB[(wn + i*16 + c16)*32 + g16*8];
    }
#pragma unroll
    for (int i = 0; i < 4; i++)
#pragma unroll
      for (int j = 0; j < 4; j++)
        acc[i][j] = mfma16(af[i], bfv[j], acc[i][j]);
  }

#pragma unroll
  for (int i = 0; i < 4; i++)
#pragma unroll
    for (int j = 0; j < 4; j++)
#pragma unroll
      for (int r = 0; r < 4; r++){
        const int row = m0 + wm + i*16 + g16*4 + r;
        const int col = n0 + wn + j*16 + c16;
        const float v = acc[i][j][r];
        if constexpr (EPI == 0){
          if (col < HID){
            o0[(size_t)row*HID + col] = (bf16)(v + bias[col]);
          } else {
            const int nn = col - HID;
            const float vv = v + bias2[nn];
            if (nn < HD) o1[(size_t)row*HD + nn] = (bf16)vv;
            else {
              const int d = nn - HD;                 // V^T: [b][d][s]
              o2[((size_t)(row >> 11)*HD + d)*SEQ + (row & (SEQ-1))] = (bf16)vv;
            }
          }
        } else if constexpr (EPI == 1){
          outf[(size_t)row*HID + col] = v + bias[col] + res[(size_t)row*HID + col];
        } else if constexpr (EPI == 2){
          const float u = v + bias[col];
          const float a2 = 1.5957691216057308f * (u + 0.044715f*u*u*u);  // 2*0.79788456*(...)
          const float th = 1.0f - 2.0f/(__expf(a2) + 1.0f);              // tanh via hw exp
          o0[(size_t)row*INTER_ + col] = (bf16)(0.5f * u * (1.0f + th));
        } else {
          float* op = outf + (size_t)row*HID + col;
          *op = v + bias[col] + *op;
        }
      }
}

// ---- causal MQA flash attention v3: barrier-free, KVBLK=64, paired q-tiles ----
// v3: first-half V fragments hoisted before softmax (hide L2 latency under shfl chain)
__global__ __launch_bounds__(256)
void attn_k(const bf16* __restrict__ qbuf, const bf16* __restrict__ kb,
            const bf16* __restrict__ vT, bf16* ob)
{
  __shared__ bf16 pl[4][16][64];
  const int bid0 = blockIdx.x;
  const int bid = ((bid0 & 7) << 7) + (bid0 >> 3);   // XCD swizzle (1024 blocks)
  const int b  = bid >> 8;
  const int h  = (bid >> 4) & 15;
  const int pr = bid & 15;
  const int t = threadIdx.x, w = t >> 6, l = t & 63;
  const int g16 = l >> 4, c16 = l & 15;
  const float scale = 0.08838834764831845f;   // 128^-0.5
  const f32x4 z4 = {0.f,0.f,0.f,0.f};
  const bf16* kbase = kb + (size_t)b*SEQ*HD;
  const bf16* vbase = vT + (size_t)b*HD*SEQ;

#pragma unroll
  for (int pass = 0; pass < 2; pass++){
    const int qb_i = pass ? (31 - pr) : pr;
    const int q0 = qb_i * 64;
    const bf16* qrow = qbuf + (size_t)(b*SEQ + q0 + w*16 + c16)*HID + h*HD + g16*8;
    bf16x8 qf[4];
#pragma unroll
    for (int dc = 0; dc < 4; dc++) qf[dc] = *(const bf16x8*)(qrow + dc*32);

    f32x4 acc[8];
#pragma unroll
    for (int i = 0; i < 8; i++) acc[i] = z4;
    float mrun[4] = {-1e30f,-1e30f,-1e30f,-1e30f};
    float lrun[4] = {0.f,0.f,0.f,0.f};
    const int qg_ = q0 + w*16 + g16*4;      // +r = global q row

    for (int kt = 0; kt <= qb_i; kt++){
      const int t0 = kt * 64;
      // ---- QK^T over 64 keys: 4 key-subtiles x 4 d-chunks ----
      f32x4 s[4] = {z4, z4, z4, z4};
#pragma unroll
      for (int ks = 0; ks < 4; ks++){
        const bf16* kr = kbase + (size_t)(t0 + ks*16 + c16)*HD + g16*8;
#pragma unroll
        for (int dc = 0; dc < 4; dc++)
          s[ks] = mfma16(qf[dc], *(const bf16x8*)(kr + dc*32), s[ks]);
      }
      // ---- hoisted V loads (dt 0..3, both k-halves): hide under softmax ----
      bf16x8 v0a[4], v1a[4];
#pragma unroll
      for (int dt = 0; dt < 4; dt++){
        const bf16* vr = vbase + (size_t)(dt*16 + c16)*SEQ + t0 + g16*8;
        v0a[dt] = *(const bf16x8*)vr;
        v1a[dt] = *(const bf16x8*)(vr + 32);
      }
      const bool last = (kt == qb_i);
      // ---- online softmax: lane holds rows qg_+r, keys t0+ks*16+c16 ----
      float coef[4];
#pragma unroll
      for (int r = 0; r < 4; r++){
        float sv[4];
#pragma unroll
        for (int ks = 0; ks < 4; ks++) sv[ks] = s[ks][r] * scale;
        if (last){
          const int qg = qg_ + r;
#pragma unroll
          for (int ks = 0; ks < 4; ks++)
            if (t0 + ks*16 + c16 > qg) sv[ks] = -1e30f;
        }
        float mv = fmaxf(fmaxf(sv[0], sv[1]), fmaxf(sv[2], sv[3]));
#pragma unroll
        for (int mk = 1; mk < 16; mk <<= 1) mv = fmaxf(mv, __shfl_xor(mv, mk));
        const float mn = fmaxf(mrun[r], mv);
        float p[4], ps = 0.f;
#pragma unroll
        for (int ks = 0; ks < 4; ks++){ p[ks] = __expf(sv[ks] - mn); ps += p[ks]; }
#pragma unroll
        for (int mk = 1; mk < 16; mk <<= 1) ps += __shfl_xor(ps, mk);
        coef[r] = __expf(mrun[r] - mn);
        lrun[r] = lrun[r]*coef[r] + ps;
        mrun[r] = mn;
#pragma unroll
        for (int ks = 0; ks < 4; ks++)
          pl[w][g16*4 + r][ks*16 + c16] = (bf16)p[ks];
      }
#pragma unroll
      for (int dt = 0; dt < 8; dt++)
#pragma unroll
        for (int r = 0; r < 4; r++) acc[dt][r] *= coef[r];
      // ---- PV: A=P from per-wave LDS, B=V^T rows (dt<4 prefetched) ----
      const bf16x8 pa0 = *(const bf16x8*)&pl[w][c16][g16*8];
      const bf16x8 pa1 = *(const bf16x8*)&pl[w][c16][32 + g16*8];
#pragma unroll
      for (int dt = 0; dt < 4; dt++){
        acc[dt] = mfma16(pa0, v0a[dt], acc[dt]);
        acc[dt] = mfma16(pa1, v1a[dt], acc[dt]);
      }
#pragma unroll
      for (int dt = 4; dt < 8; dt++){
        const bf16* vr = vbase + (size_t)(dt*16 + c16)*SEQ + t0 + g16*8;
        acc[dt] = mfma16(pa0, *(const bf16x8*)vr,        acc[dt]);
        acc[dt] = mfma16(pa1, *(const bf16x8*)(vr + 32), acc[dt]);
      }
    }
#pragma unroll
    for (int r = 0; r < 4; r++){
      const float inv = 1.0f / lrun[r];
      bf16* orow = ob + (size_t)(b*SEQ + qg_ + r)*HID + h*HD;
#pragma unroll
      for (int dt = 0; dt < 8; dt++)
        orow[dt*16 + c16] = (bf16)(acc[dt][r] * inv);
    }
  }
}

extern "C" void kernel_launch(void* const* d_in, const int* in_sizes, int n_in,
                              void* d_out, int out_size, void* d_ws, size_t ws_size,
                              hipStream_t stream)
{
  const float* x    = (const float*)d_in[0];
  const float* ln1g = (const float*)d_in[1];
  const float* ln1b = (const float*)d_in[2];
  const float* ln2g = (const float*)d_in[3];
  const float* ln2b = (const float*)d_in[4];
  const float* wq   = (const float*)d_in[5];
  const float* bq   = (const float*)d_in[6];
  const float* wkv  = (const float*)d_in[7];
  const float* bkv  = (const float*)d_in[8];
  const float* wo   = (const float*)d_in[9];
  const float* bo   = (const float*)d_in[10];
  const float* wfc  = (const float*)d_in[11];
  const float* bfc  = (const float*)d_in[12];
  const float* wpr  = (const float*)d_in[13];
  const float* bpr  = (const float*)d_in[14];
  float* out = (float*)d_out;
  (void)in_sizes; (void)n_in; (void)out_size; (void)ws_size;

  char* p = (char*)d_ws;
  auto carve = [&](size_t n){ char* r = p; p += (n + 255) & ~(size_t)255; return r; };
  bf16* wqkvT = (bf16*)carve((size_t)2304*2048*2);   //  9.4 MB
  bf16* woT   = (bf16*)carve((size_t)2048*2048*2);   //  8.4 MB
  bf16* wfcT  = (bf16*)carve((size_t)8192*2048*2);   // 33.6 MB
  bf16* wprT  = (bf16*)carve((size_t)2048*8192*2);   // 33.6 MB
  bf16* hbuf  = (bf16*)carve((size_t)NTOK*2048*2);   // 33.6 MB (LN1 out, later LN2 out)
  bf16* qbuf  = (bf16*)carve((size_t)NTOK*2048*2);   // 33.6 MB (Q; attn output in-place)
  bf16* kbuf  = (bf16*)carve((size_t)NTOK*128*2);    //  2.1 MB
  bf16* vbufT = (bf16*)carve((size_t)NTOK*128*2);    //  2.1 MB (V^T [b][d][s])
  // MLP inter buffer (grows=4096 rows x 8192): ALIASES qbuf/kbuf/vbufT (dead
  // after the WO GEMM) + a 29.3MB extension. Total ws = 185.6MB (< 190MB proven).
  const size_t grows = 4096;
  {
    const size_t span = (size_t)(p - (char*)qbuf);
    const size_t need = grows * (size_t)INTER_ * 2;
    if (need > span) carve(need - span);
  }
  bf16* gbuf = qbuf;

  dim3 B(256);
  convT_k<<<dim3(64, 64),  B, 0, stream>>>(wq,  wqkvT, 2048, 2048);
  convT_k<<<dim3(64, 8),   B, 0, stream>>>(wkv, wqkvT + (size_t)2048*2048, 2048, 256);
  convT_k<<<dim3(64, 64),  B, 0, stream>>>(wo,  woT,  2048, 2048);
  convT_k<<<dim3(64, 256), B, 0, stream>>>(wfc, wfcT, 2048, 8192);
  convT_k<<<dim3(256, 64), B, 0, stream>>>(wpr, wprT, 8192, 2048);

  ln_k<<<NTOK, B, 0, stream>>>(x, ln1g, ln1b, hbuf);
  gemm_bt<0><<<dim3(64, 18), B, 0, stream>>>(hbuf, wqkvT, NTOK, 2304, 2048,
                                             bq, bkv, nullptr, nullptr, qbuf, kbuf, vbufT);
  attn_k<<<1024, B, 0, stream>>>(qbuf, kbuf, vbufT, qbuf /*in-place*/);
  gemm_bt<1><<<dim3(64, 16), B, 0, stream>>>(qbuf, woT, NTOK, 2048, 2048,
                                             bo, nullptr, x, out, nullptr, nullptr, nullptr);
  ln_k<<<NTOK, B, 0, stream>>>(out, ln2g, ln2b, hbuf);
  for (size_t c = 0; c < NTOK/grows; c++){
    const size_t ro = c * grows;
    gemm_bt<2><<<dim3(grows/128, 64), B, 0, stream>>>(hbuf + ro*HID, wfcT, (int)grows, 8192, 2048,
                                               bfc, nullptr, nullptr, nullptr, gbuf, nullptr, nullptr);
    gemm_bt<3><<<dim3(grows/128, 16), B, 0, stream>>>(gbuf, wprT, (int)grows, 2048, 8192,
                                               bpr, nullptr, nullptr, out + ro*HID, nullptr, nullptr, nullptr);
  }
}

// Round 10
// 1771.146 us; speedup vs baseline: 1.3416x; 1.0996x over previous
//
#include <hip/hip_runtime.h>
#include <hip/hip_bf16.h>
#include <math.h>

typedef __bf16 bf16;
typedef __bf16 bf16x8 __attribute__((ext_vector_type(8)));
typedef float  f32x4  __attribute__((ext_vector_type(4)));

#define HID    2048
#define INTER_ 8192
#define SEQ    2048
#define NTOK   8192
#define HD     128

__device__ __forceinline__ f32x4 mfma16(bf16x8 a, bf16x8 b, f32x4 c){
  return __builtin_amdgcn_mfma_f32_16x16x32_bf16(a, b, c, 0, 0, 0);
}

__device__ __forceinline__ void gl_lds16(const void* g, void* l){
  __builtin_amdgcn_global_load_lds((const __attribute__((address_space(1))) void*)g,
                                   (__attribute__((address_space(3))) void*)l,
                                   16, 0, 0);
}

// ---- fp32 [K][N]  ->  bf16 [N][K] (transpose + convert) ----
__global__ __launch_bounds__(256)
void convT_k(const float* __restrict__ in, bf16* __restrict__ out, int K, int N)
{
  __shared__ float tile[32][33];
  const int k0 = blockIdx.x * 32, n0 = blockIdx.y * 32;
  const int tx = threadIdx.x & 31, ty = threadIdx.x >> 5;  // 32 x 8
#pragma unroll
  for (int r = 0; r < 4; r++)
    tile[ty + r*8][tx] = in[(size_t)(k0 + ty + r*8) * N + n0 + tx];
  __syncthreads();
#pragma unroll
  for (int r = 0; r < 4; r++)
    out[(size_t)(n0 + ty + r*8) * K + k0 + tx] = (bf16)tile[tx][ty + r*8];
}

// ---- LayerNorm (fp32 in, bf16 out), one block per token ----
__global__ __launch_bounds__(256)
void ln_k(const float* __restrict__ x, const float* __restrict__ gamma,
          const float* __restrict__ beta, bf16* __restrict__ out)
{
  const int row = blockIdx.x, t = threadIdx.x;
  const float* xr = x + (size_t)row * HID;
  const float4 a = ((const float4*)xr)[t*2];
  const float4 b = ((const float4*)xr)[t*2 + 1];
  float s  = a.x+a.y+a.z+a.w + b.x+b.y+b.z+b.w;
  float ss = a.x*a.x+a.y*a.y+a.z*a.z+a.w*a.w + b.x*b.x+b.y*b.y+b.z*b.z+b.w*b.w;
#pragma unroll
  for (int m = 32; m; m >>= 1){ s += __shfl_xor(s, m); ss += __shfl_xor(ss, m); }
  __shared__ float red[8];
  const int w = t >> 6;
  if ((t & 63) == 0){ red[w*2] = s; red[w*2+1] = ss; }
  __syncthreads();
  s  = red[0] + red[2] + red[4] + red[6];
  ss = red[1] + red[3] + red[5] + red[7];
  const float mean = s * (1.0f/HID);
  const float var  = ss * (1.0f/HID) - mean*mean;
  const float rs   = rsqrtf(var + 1e-5f);
  const int c = t * 8;
  const float xe[8] = {a.x,a.y,a.z,a.w,b.x,b.y,b.z,b.w};
  bf16x8 o;
#pragma unroll
  for (int e = 0; e < 8; e++)
    o[e] = (bf16)((xe[e] - mean) * rs * gamma[c+e] + beta[c+e]);
  *(bf16x8*)(out + (size_t)row*HID + c) = o;
}

// ---- GEMM: C[M][N] = A[M][K] * BT[N][K]^T, 128x128 tile, BK=32, 4 waves ----
// EPI 0: QKV split -> o0=q bf16 [tok][2048], o1=k [tok][128], o2=V^T [b][d][s]
// EPI 1: + bias + res -> outf fp32
// EPI 2: + bias, gelu -> o0 bf16 (stride INTER_)
// EPI 3: + bias + outf(read) -> outf fp32
template<int EPI>
__global__ __launch_bounds__(256)
void gemm_bt(const bf16* __restrict__ A, const bf16* __restrict__ BT,
             int M, int N, int K,
             const float* __restrict__ bias, const float* __restrict__ bias2,
             const float* __restrict__ res, float* __restrict__ outf,
             bf16* __restrict__ o0, bf16* __restrict__ o1, bf16* __restrict__ o2)
{
  __shared__ bf16 lA[128*32];
  __shared__ bf16 lB[128*32];
  const int t = threadIdx.x, l = t & 63, w = t >> 6;
  // XCD-aware bijective block swizzle (all launches have nwg % 8 == 0)
  int bx = blockIdx.x, by = blockIdx.y;
  {
    const int nwg = gridDim.x * gridDim.y;
    if ((nwg & 7) == 0){
      int wg = by * gridDim.x + bx;
      const int per = nwg >> 3;
      wg = (wg & 7) * per + (wg >> 3);
      bx = wg % gridDim.x; by = wg / gridDim.x;
    }
  }
  const int m0 = bx * 128, n0 = by * 128;
  const int wm = (w >> 1) * 64, wn = (w & 1) * 64;
  const int g16 = l >> 4, c16 = l & 15;
  const f32x4 z4 = {0.f, 0.f, 0.f, 0.f};
  f32x4 acc[4][4];
#pragma unroll
  for (int i = 0; i < 4; i++)
#pragma unroll
    for (int j = 0; j < 4; j++) acc[i][j] = z4;

  const int srow = (t * 16) >> 6;          // staging row 0..63
  const int scol = ((t * 16) & 63) >> 1;   // bf16 elem offset within 32-wide row

  for (int k0 = 0; k0 < K; k0 += 32){
    __syncthreads();
    gl_lds16(A  + (size_t)(m0 + srow)      * K + k0 + scol, (char*)lA + t*16);
    gl_lds16(A  + (size_t)(m0 + 64 + srow) * K + k0 + scol, (char*)lA + 4096 + t*16);
    gl_lds16(BT + (size_t)(n0 + srow)      * K + k0 + scol, (char*)lB + t*16);
    gl_lds16(BT + (size_t)(n0 + 64 + srow) * K + k0 + scol, (char*)lB + 4096 + t*16);
    __syncthreads();
    bf16x8 af[4], bfv[4];
#pragma unroll
    for (int i = 0; i < 4; i++){
      af[i]  = *(const bf16x8*)&lA[(wm + i*16 + c16)*32 + g16*8];
      bfv[i] = *(const bf16x8*)&lB[(wn + i*16 + c16)*32 + g16*8];
    }
#pragma unroll
    for (int i = 0; i < 4; i++)
#pragma unroll
      for (int j = 0; j < 4; j++)
        acc[i][j] = mfma16(af[i], bfv[j], acc[i][j]);
  }

#pragma unroll
  for (int i = 0; i < 4; i++)
#pragma unroll
    for (int j = 0; j < 4; j++)
#pragma unroll
      for (int r = 0; r < 4; r++){
        const int row = m0 + wm + i*16 + g16*4 + r;
        const int col = n0 + wn + j*16 + c16;
        const float v = acc[i][j][r];
        if constexpr (EPI == 0){
          if (col < HID){
            o0[(size_t)row*HID + col] = (bf16)(v + bias[col]);
          } else {
            const int nn = col - HID;
            const float vv = v + bias2[nn];
            if (nn < HD) o1[(size_t)row*HD + nn] = (bf16)vv;
            else {
              const int d = nn - HD;                 // V^T: [b][d][s]
              o2[((size_t)(row >> 11)*HD + d)*SEQ + (row & (SEQ-1))] = (bf16)vv;
            }
          }
        } else if constexpr (EPI == 1){
          outf[(size_t)row*HID + col] = v + bias[col] + res[(size_t)row*HID + col];
        } else if constexpr (EPI == 2){
          const float u = v + bias[col];
          const float a2 = 1.5957691216057308f * (u + 0.044715f*u*u*u);  // 2*0.79788456*(...)
          const float th = 1.0f - 2.0f/(__expf(a2) + 1.0f);              // tanh via hw exp
          o0[(size_t)row*INTER_ + col] = (bf16)(0.5f * u * (1.0f + th));
        } else {
          float* op = outf + (size_t)row*HID + col;
          *op = v + bias[col] + *op;
        }
      }
}

// ---- causal MQA flash attention v4: LDS-staged K (double-buffered, XOR-swizzled),
// KVBLK=64, paired q-tiles. K staged ONCE per block (was 4x redundant per-wave L2
// loads); stage of tile kt+1 overlaps compute of kt; one __syncthreads per tile.
// Swizzle (T21): LDS dest linear, SOURCE global col pre-swizzled cb^((row&7)<<4),
// reads apply same XOR. V read from global V^T (dt<4 hoisted before softmax).
__global__ __launch_bounds__(256)
void attn_k(const bf16* __restrict__ qbuf, const bf16* __restrict__ kb,
            const bf16* __restrict__ vT, bf16* ob)
{
  __shared__ bf16 lK[2][64][128];  // 32 KB, swizzled
  __shared__ bf16 pl[4][16][64];   //  8 KB
  const int bid0 = blockIdx.x;
  const int bid = ((bid0 & 7) << 7) + (bid0 >> 3);   // XCD swizzle (1024 blocks)
  const int b  = bid >> 8;
  const int h  = (bid >> 4) & 15;
  const int pr = bid & 15;
  const int t = threadIdx.x, w = t >> 6, l = t & 63;
  const int g16 = l >> 4, c16 = l & 15;
  const float scale = 0.08838834764831845f;   // 128^-0.5
  const f32x4 z4 = {0.f,0.f,0.f,0.f};
  const bf16* kbase = kb + (size_t)b*SEQ*HD;
  const bf16* vbase = vT + (size_t)b*HD*SEQ;
  const int kswz = (c16 & 7) << 4;            // read-side XOR for this lane's K rows

  // staging: 1024 16B slots over 256 threads; slot=i*256+t; row=slot>>4
  int srow4[4], scb4[4];
#pragma unroll
  for (int i = 0; i < 4; i++){
    const int slot = i*256 + t;
    srow4[i] = slot >> 4;
    scb4[i]  = ((slot & 15) * 16) ^ ((srow4[i] & 7) << 4);
  }
  auto stageK = [&](int bsel, int tile0){
#pragma unroll
    for (int i = 0; i < 4; i++)
      gl_lds16((const char*)kbase + ((size_t)(tile0 + srow4[i])*HD)*2 + scb4[i],
               (char*)lK + bsel*16384 + (i*256 + t)*16);
  };

  int buf = 0;
#pragma unroll
  for (int pass = 0; pass < 2; pass++){
    const int qb_i = pass ? (31 - pr) : pr;
    const int q0 = qb_i * 64;
    const bf16* qrow = qbuf + (size_t)(b*SEQ + q0 + w*16 + c16)*HID + h*HD + g16*8;
    bf16x8 qf[4];
#pragma unroll
    for (int dc = 0; dc < 4; dc++) qf[dc] = *(const bf16x8*)(qrow + dc*32);

    f32x4 acc[8];
#pragma unroll
    for (int i = 0; i < 8; i++) acc[i] = z4;
    float mrun[4] = {-1e30f,-1e30f,-1e30f,-1e30f};
    float lrun[4] = {0.f,0.f,0.f,0.f};
    const int qg_ = q0 + w*16 + g16*4;      // +r = global q row

    stageK(buf, 0);
    __syncthreads();

    for (int kt = 0; kt <= qb_i; kt++){
      const int t0 = kt * 64;
      if (kt < qb_i) stageK(buf ^ 1, t0 + 64);   // prefetch next tile (hides under compute)
      // ---- QK^T from swizzled LDS K: 4 key-subtiles x 4 d-chunks ----
      f32x4 s[4] = {z4, z4, z4, z4};
      const char* lkb = (const char*)lK + buf*16384;
#pragma unroll
      for (int ks = 0; ks < 4; ks++){
        const char* krow = lkb + (ks*16 + c16)*256;
#pragma unroll
        for (int dc = 0; dc < 4; dc++){
          const bf16x8 kf = *(const bf16x8*)(krow + ((dc*64 + g16*16) ^ kswz));
          s[ks] = mfma16(qf[dc], kf, s[ks]);
        }
      }
      // ---- hoisted V loads (dt 0..3, both k-halves): hide under softmax ----
      bf16x8 v0a[4], v1a[4];
#pragma unroll
      for (int dt = 0; dt < 4; dt++){
        const bf16* vr = vbase + (size_t)(dt*16 + c16)*SEQ + t0 + g16*8;
        v0a[dt] = *(const bf16x8*)vr;
        v1a[dt] = *(const bf16x8*)(vr + 32);
      }
      const bool last = (kt == qb_i);
      // ---- online softmax: lane holds rows qg_+r, keys t0+ks*16+c16 ----
      float coef[4];
#pragma unroll
      for (int r = 0; r < 4; r++){
        float sv[4];
#pragma unroll
        for (int ks = 0; ks < 4; ks++) sv[ks] = s[ks][r] * scale;
        if (last){
          const int qg = qg_ + r;
#pragma unroll
          for (int ks = 0; ks < 4; ks++)
            if (t0 + ks*16 + c16 > qg) sv[ks] = -1e30f;
        }
        float mv = fmaxf(fmaxf(sv[0], sv[1]), fmaxf(sv[2], sv[3]));
#pragma unroll
        for (int mk = 1; mk < 16; mk <<= 1) mv = fmaxf(mv, __shfl_xor(mv, mk));
        const float mn = fmaxf(mrun[r], mv);
        float p[4], ps = 0.f;
#pragma unroll
        for (int ks = 0; ks < 4; ks++){ p[ks] = __expf(sv[ks] - mn); ps += p[ks]; }
#pragma unroll
        for (int mk = 1; mk < 16; mk <<= 1) ps += __shfl_xor(ps, mk);
        coef[r] = __expf(mrun[r] - mn);
        lrun[r] = lrun[r]*coef[r] + ps;
        mrun[r] = mn;
#pragma unroll
        for (int ks = 0; ks < 4; ks++)
          pl[w][g16*4 + r][ks*16 + c16] = (bf16)p[ks];
      }
#pragma unroll
      for (int dt = 0; dt < 8; dt++)
#pragma unroll
        for (int r = 0; r < 4; r++) acc[dt][r] *= coef[r];
      // ---- PV: A=P from per-wave LDS, B=V^T rows (dt<4 prefetched) ----
      const bf16x8 pa0 = *(const bf16x8*)&pl[w][c16][g16*8];
      const bf16x8 pa1 = *(const bf16x8*)&pl[w][c16][32 + g16*8];
#pragma unroll
      for (int dt = 0; dt < 4; dt++){
        acc[dt] = mfma16(pa0, v0a[dt], acc[dt]);
        acc[dt] = mfma16(pa1, v1a[dt], acc[dt]);
      }
#pragma unroll
      for (int dt = 4; dt < 8; dt++){
        const bf16* vr = vbase + (size_t)(dt*16 + c16)*SEQ + t0 + g16*8;
        acc[dt] = mfma16(pa0, *(const bf16x8*)vr,        acc[dt]);
        acc[dt] = mfma16(pa1, *(const bf16x8*)(vr + 32), acc[dt]);
      }
      __syncthreads();                       // stage(kt+1) done; reads of buf done
      buf ^= 1;
    }
#pragma unroll
    for (int r = 0; r < 4; r++){
      const float inv = 1.0f / lrun[r];
      bf16* orow = ob + (size_t)(b*SEQ + qg_ + r)*HID + h*HD;
#pragma unroll
      for (int dt = 0; dt < 8; dt++)
        orow[dt*16 + c16] = (bf16)(acc[dt][r] * inv);
    }
  }
}

extern "C" void kernel_launch(void* const* d_in, const int* in_sizes, int n_in,
                              void* d_out, int out_size, void* d_ws, size_t ws_size,
                              hipStream_t stream)
{
  const float* x    = (const float*)d_in[0];
  const float* ln1g = (const float*)d_in[1];
  const float* ln1b = (const float*)d_in[2];
  const float* ln2g = (const float*)d_in[3];
  const float* ln2b = (const float*)d_in[4];
  const float* wq   = (const float*)d_in[5];
  const float* bq   = (const float*)d_in[6];
  const float* wkv  = (const float*)d_in[7];
  const float* bkv  = (const float*)d_in[8];
  const float* wo   = (const float*)d_in[9];
  const float* bo   = (const float*)d_in[10];
  const float* wfc  = (const float*)d_in[11];
  const float* bfc  = (const float*)d_in[12];
  const float* wpr  = (const float*)d_in[13];
  const float* bpr  = (const float*)d_in[14];
  float* out = (float*)d_out;
  (void)in_sizes; (void)n_in; (void)out_size; (void)ws_size;

  char* p = (char*)d_ws;
  auto carve = [&](size_t n){ char* r = p; p += (n + 255) & ~(size_t)255; return r; };
  bf16* wqkvT = (bf16*)carve((size_t)2304*2048*2);   //  9.4 MB
  bf16* woT   = (bf16*)carve((size_t)2048*2048*2);   //  8.4 MB
  bf16* wfcT  = (bf16*)carve((size_t)8192*2048*2);   // 33.6 MB
  bf16* wprT  = (bf16*)carve((size_t)2048*8192*2);   // 33.6 MB
  bf16* hbuf  = (bf16*)carve((size_t)NTOK*2048*2);   // 33.6 MB (LN1 out, later LN2 out)
  bf16* qbuf  = (bf16*)carve((size_t)NTOK*2048*2);   // 33.6 MB (Q; attn output in-place)
  bf16* kbuf  = (bf16*)carve((size_t)NTOK*128*2);    //  2.1 MB
  bf16* vbufT = (bf16*)carve((size_t)NTOK*128*2);    //  2.1 MB (V^T [b][d][s])
  // MLP inter buffer (grows=4096 rows x 8192): ALIASES qbuf/kbuf/vbufT (dead
  // after the WO GEMM) + a 29.3MB extension. Total ws = 185.6MB (< 190MB proven).
  const size_t grows = 4096;
  {
    const size_t span = (size_t)(p - (char*)qbuf);
    const size_t need = grows * (size_t)INTER_ * 2;
    if (need > span) carve(need - span);
  }
  bf16* gbuf = qbuf;

  dim3 B(256);
  convT_k<<<dim3(64, 64),  B, 0, stream>>>(wq,  wqkvT, 2048, 2048);
  convT_k<<<dim3(64, 8),   B, 0, stream>>>(wkv, wqkvT + (size_t)2048*2048, 2048, 256);
  convT_k<<<dim3(64, 64),  B, 0, stream>>>(wo,  woT,  2048, 2048);
  convT_k<<<dim3(64, 256), B, 0, stream>>>(wfc, wfcT, 2048, 8192);
  convT_k<<<dim3(256, 64), B, 0, stream>>>(wpr, wprT, 8192, 2048);

  ln_k<<<NTOK, B, 0, stream>>>(x, ln1g, ln1b, hbuf);
  gemm_bt<0><<<dim3(64, 18), B, 0, stream>>>(hbuf, wqkvT, NTOK, 2304, 2048,
                                             bq, bkv, nullptr, nullptr, qbuf, kbuf, vbufT);
  attn_k<<<1024, B, 0, stream>>>(qbuf, kbuf, vbufT, qbuf /*in-place*/);
  gemm_bt<1><<<dim3(64, 16), B, 0, stream>>>(qbuf, woT, NTOK, 2048, 2048,
                                             bo, nullptr, x, out, nullptr, nullptr, nullptr);
  ln_k<<<NTOK, B, 0, stream>>>(out, ln2g, ln2b, hbuf);
  for (size_t c = 0; c < NTOK/grows; c++){
    const size_t ro = c * grows;
    gemm_bt<2><<<dim3(grows/128, 64), B, 0, stream>>>(hbuf + ro*HID, wfcT, (int)grows, 8192, 2048,
                                               bfc, nullptr, nullptr, nullptr, gbuf, nullptr, nullptr);
    gemm_bt<3><<<dim3(grows/128, 16), B, 0, stream>>>(gbuf, wprT, (int)grows, 2048, 8192,
                                               bpr, nullptr, nullptr, out + ro*HID, nullptr, nullptr, nullptr);
  }
}